// Round 9
// baseline (468.077 us; speedup 1.0000x reference)
//
#include <hip/hip_runtime.h>
#include <math.h>

#define S_LEN 2048
#define DMODEL 2560
#define NH 32
#define NKV 8
#define HD 128
#define QDIM (NH*HD)     // 4096
#define KVDIM (NKV*HD)   // 1024
#define ROPE_THETA 5000000.0
#define QK_SCALE 0.08838834764831843f

typedef __attribute__((ext_vector_type(8))) short s16x8;
typedef __attribute__((ext_vector_type(4))) float f32x4;
typedef __attribute__((ext_vector_type(16))) float f32x16;
typedef unsigned short u16;

#define MFMA16(a,b,c) __builtin_amdgcn_mfma_f32_16x16x32_bf16((a),(b),(c),0,0,0)
#define MFMA32(a,b,c) __builtin_amdgcn_mfma_f32_32x32x16_bf16((a),(b),(c),0,0,0)

__device__ __forceinline__ u16 f2bf(float x) {
    union { float f; unsigned u; } v; v.f = x;
    unsigned r = v.u + 0x7FFFu + ((v.u >> 16) & 1u);
    return (u16)(r >> 16);
}
__device__ __forceinline__ float bf2f(u16 h) {
    union { unsigned u; float f; } v; v.u = ((unsigned)h) << 16;
    return v.f;
}
__device__ __forceinline__ unsigned pk2(float a, float b) {
    return (unsigned)f2bf(a) | ((unsigned)f2bf(b) << 16);
}

// Swizzled LDS index, CKU units of 8 bf16 per row; XOR low-3 bits of unit.
__device__ __forceinline__ int lsw(int row, int kb, int CKU) {
    return (((row * CKU + kb) ^ (row & 7)) << 3);
}
// K arrays: CKU=16, XOR all 4 unit bits (full 256B spread).
__device__ __forceinline__ int lswK(int row, int kb) {
    return ((row * 16 + (kb ^ (row & 15))) << 3);
}

// async global->LDS, 16B per lane; LDS dest = wave-uniform base + lane*16.
__device__ __forceinline__ void gload16(const void* g, void* l) {
    __builtin_amdgcn_global_load_lds(
        (const __attribute__((address_space(1))) void*)g,
        (__attribute__((address_space(3))) void*)l, 16, 0, 0);
}

// ---------------------------------------------------------------------------
// prep_all: all input-side elementwise work in ONE launch.
// ---------------------------------------------------------------------------
#define N4_X   (S_LEN*DMODEL/4)      // 1310720
#define N4_WQ  (QDIM*DMODEL/4)       // 2621440
#define N4_WKV (KVDIM*DMODEL/4)      // 655360
#define N4_WO  (DMODEL*QDIM/4)       // 2621440
#define N_TAB  (S_LEN*64)            // 131072
#define PREP_TOTAL (N4_X + N4_WQ + N4_WKV + N4_WKV + N4_WO + N_TAB)

__device__ __forceinline__ void split4(const float* in, long i,
                                       u16* hi, u16* lo) {
    float4 v = ((const float4*)in)[i];
    float a[4] = {v.x, v.y, v.z, v.w};
    u16 hh[4], ll[4];
    #pragma unroll
    for (int j = 0; j < 4; ++j) {
        hh[j] = f2bf(a[j]);
        ll[j] = f2bf(a[j] - bf2f(hh[j]));
    }
    ((uint2*)hi)[i] = make_uint2((unsigned)hh[0] | ((unsigned)hh[1] << 16),
                                 (unsigned)hh[2] | ((unsigned)hh[3] << 16));
    ((uint2*)lo)[i] = make_uint2((unsigned)ll[0] | ((unsigned)ll[1] << 16),
                                 (unsigned)ll[2] | ((unsigned)ll[3] << 16));
}
__device__ __forceinline__ void cvt4(const float* in, long i, u16* out) {
    float4 v = ((const float4*)in)[i];
    u16 h0 = f2bf(v.x), h1 = f2bf(v.y), h2 = f2bf(v.z), h3 = f2bf(v.w);
    ((uint2*)out)[i] = make_uint2((unsigned)h0 | ((unsigned)h1 << 16),
                                  (unsigned)h2 | ((unsigned)h3 << 16));
}

__global__ __launch_bounds__(256)
void prep_all(const float* __restrict__ x, const float* __restrict__ w_q,
              const float* __restrict__ w_k, const float* __restrict__ w_v,
              const float* __restrict__ w_o, const int* __restrict__ pos,
              u16* __restrict__ XH, u16* __restrict__ XL,
              u16* __restrict__ WQH, u16* __restrict__ WQL,
              u16* __restrict__ WKH, u16* __restrict__ WKL,
              u16* __restrict__ WVH, u16* __restrict__ WOH,
              float* __restrict__ cost, float* __restrict__ sint) {
    long i = (long)blockIdx.x * 256 + threadIdx.x;
    if (i < N4_X) { split4(x, i, XH, XL); return; }
    i -= N4_X;
    if (i < N4_WQ) { split4(w_q, i, WQH, WQL); return; }
    i -= N4_WQ;
    if (i < N4_WKV) { split4(w_k, i, WKH, WKL); return; }
    i -= N4_WKV;
    if (i < N4_WKV) { cvt4(w_v, i, WVH); return; }
    i -= N4_WKV;
    if (i < N4_WO) { cvt4(w_o, i, WOH); return; }
    i -= N4_WO;
    if (i < N_TAB) {
        int s = (int)(i >> 6), j = (int)(i & 63);
        double inv = pow((double)ROPE_THETA, -(double)j / 64.0);
        double ang = (double)pos[s] * inv;
        cost[i] = (float)cos(ang);
        sint[i] = (float)sin(ang);
    }
}

// ---------------------------------------------------------------------------
// merged rope: q (scaled, ws) + k (in-place fp32 cache) -> bf16 hi/lo splits
// ---------------------------------------------------------------------------
__global__ __launch_bounds__(256)
void rope_qk_split(float* __restrict__ q32, float* __restrict__ k,
                   const float* __restrict__ cost, const float* __restrict__ sint,
                   u16* __restrict__ qhh, u16* __restrict__ qll,
                   u16* __restrict__ khh, u16* __restrict__ kll) {
    int idx = blockIdx.x * 256 + threadIdx.x;
    if (idx < S_LEN * NH * 64) {
        int j = idx & 63;
        int h = (idx >> 6) & 31;
        int s = idx >> 11;
        float c = cost[(s << 6) + j], sn = sint[(s << 6) + j];
        size_t base = (size_t)s * QDIM + (size_t)h * HD;
        float x1 = q32[base + j], x2 = q32[base + 64 + j];
        float y1 = (x1 * c - x2 * sn) * QK_SCALE;
        float y2 = (x2 * c + x1 * sn) * QK_SCALE;
        u16 h1 = f2bf(y1), h2 = f2bf(y2);
        qhh[base + j] = h1;      qll[base + j] = f2bf(y1 - bf2f(h1));
        qhh[base + 64 + j] = h2; qll[base + 64 + j] = f2bf(y2 - bf2f(h2));
    } else {
        idx -= S_LEN * NH * 64;
        int j = idx & 63;
        int s = (idx >> 6) & 2047;
        int h = idx >> 17;
        float c = cost[(s << 6) + j], sn = sint[(s << 6) + j];
        size_t base = ((size_t)h * S_LEN + s) * HD;
        float x1 = k[base + j], x2 = k[base + 64 + j];
        float y1 = x1 * c - x2 * sn;
        float y2 = x2 * c + x1 * sn;
        k[base + j] = y1; k[base + 64 + j] = y2;
        u16 h1 = f2bf(y1), h2 = f2bf(y2);
        khh[base + j] = h1;      kll[base + j] = f2bf(y1 - bf2f(h1));
        khh[base + 64 + j] = h2; kll[base + 64 + j] = f2bf(y2 - bf2f(h2));
    }
}

// ---------------------------------------------------------------------------
// V^T builder: v [8][2048][128] fp32 -> vt [8][128][2048] bf16 (coalesced).
// ---------------------------------------------------------------------------
__global__ __launch_bounds__(256)
void vt_transpose(const float* __restrict__ v, u16* __restrict__ vt) {
    __shared__ u16 t[64][80];
    const int kvh = blockIdx.y;
    const int st = blockIdx.x >> 1, dt = blockIdx.x & 1;
    const int tid = threadIdx.x;
    const int r = tid & 15, c4 = (tid >> 4) * 4;
    const float* vb = v + ((size_t)kvh * S_LEN + st * 64) * HD + dt * 64;
    #pragma unroll
    for (int p = 0; p < 4; ++p) {
        int row = p * 16 + r;
        float4 x = *(const float4*)&vb[(size_t)row * HD + c4];
        t[c4 + 0][row] = f2bf(x.x);
        t[c4 + 1][row] = f2bf(x.y);
        t[c4 + 2][row] = f2bf(x.z);
        t[c4 + 3][row] = f2bf(x.w);
    }
    __syncthreads();
    #pragma unroll
    for (int p = 0; p < 2; ++p) {
        int idx = p * 256 + tid;
        int dr = idx >> 3, sc = idx & 7;
        size_t o = ((size_t)kvh * HD + dt * 64 + dr) * S_LEN + st * 64 + sc * 8;
        *(int4*)&vt[o] = *(const int4*)&t[dr][sc * 8];
    }
}

// ---------------------------------------------------------------------------
// Segmented plain-bf16 MFMA GEMM (NT). 128x128, BK=64, 32KB LDS.
// ---------------------------------------------------------------------------
__device__ __forceinline__ void gemm_seg_body(
    u16* lds, const u16* __restrict__ a0, const u16* __restrict__ a1,
    const u16* __restrict__ a2, const u16* __restrict__ b0,
    const u16* __restrict__ b1, const u16* __restrict__ b2,
    float* __restrict__ C, int N, int Kb, int nseg, int m0, int n0, int cmode) {
    u16* As = lds;
    u16* Bs = lds + 8192;
    const int tid = threadIdx.x;
    const int lane = tid & 63, w = tid >> 6;
    const int q4 = lane >> 4, r15 = lane & 15;
    const int wm = (w >> 1) * 64, wn = (w & 1) * 64;

    f32x4 acc[4][4];
    #pragma unroll
    for (int i = 0; i < 4; ++i)
        #pragma unroll
        for (int j = 0; j < 4; ++j) acc[i][j] = (f32x4)(0.0f);

    const int KT = nseg * Kb;
    for (int k0 = 0; k0 < KT; k0 += 64) {
        const int si = (k0 >= 2 * Kb) ? 2 : ((k0 >= Kb) ? 1 : 0);
        const int koff = k0 - si * Kb;
        const u16* Ag = (si == 0) ? a0 : ((si == 1) ? a1 : a2);
        const u16* Bg = (si == 0) ? b0 : ((si == 1) ? b1 : b2);
        __syncthreads();
        for (int ch = w; ch < 16; ch += 4) {
            int u = ch * 64 + lane;
            int row = u >> 3;
            int kb = (u & 7) ^ (row & 7);
            size_t go = (size_t)row * Kb + koff + kb * 8;
            gload16(Ag + (size_t)m0 * Kb + go, &As[ch * 512]);
            gload16(Bg + (size_t)n0 * Kb + go, &Bs[ch * 512]);
        }
        __syncthreads();   // drains vmcnt(0): LDS tiles ready

        #pragma unroll
        for (int kh2 = 0; kh2 < 2; ++kh2) {
            int kb = kh2 * 4 + q4;
            s16x8 ah[4], bh[4];
            #pragma unroll
            for (int i = 0; i < 4; ++i) ah[i] = *(const s16x8*)&As[lsw(wm + i * 16 + r15, kb, 8)];
            #pragma unroll
            for (int j = 0; j < 4; ++j) bh[j] = *(const s16x8*)&Bs[lsw(wn + j * 16 + r15, kb, 8)];
            #pragma unroll
            for (int i = 0; i < 4; ++i)
                #pragma unroll
                for (int j = 0; j < 4; ++j)
                    acc[i][j] = MFMA16(ah[i], bh[j], acc[i][j]);
        }
    }

    // epilogue: D layout col = lane&15, row = (lane>>4)*4 + r
    #pragma unroll
    for (int i = 0; i < 4; ++i) {
        #pragma unroll
        for (int j = 0; j < 4; ++j) {
            int col = n0 + wn + j * 16 + r15;
            #pragma unroll
            for (int r = 0; r < 4; ++r) {
                int row = m0 + wm + i * 16 + q4 * 4 + r;
                float val = acc[i][j][r];
                if (cmode == 0)
                    C[(size_t)row * N + col] = val;
                else
                    C[((size_t)(col >> 7) * S_LEN + row) * HD + (col & 127)] = val;
            }
        }
    }
}

// fused Q/K/V projection: grid (48, 16)
__global__ __launch_bounds__(256)
void gemm_qkv2(const u16* __restrict__ XH, const u16* __restrict__ XL,
               const u16* __restrict__ WQH, const u16* __restrict__ WQL,
               const u16* __restrict__ WKH, const u16* __restrict__ WKL,
               const u16* __restrict__ WVH,
               float* __restrict__ Q32, float* __restrict__ out_k,
               float* __restrict__ out_v) {
    __shared__ u16 lds[16384];
    const int bx = blockIdx.x, m0 = blockIdx.y * 128;
    if (bx < 32)        // Q: xh.wqh + xh.wql + xl.wqh
        gemm_seg_body(lds, XH, XH, XL, WQH, WQL, WQH, Q32, QDIM, DMODEL, 3, m0, bx * 128, 0);
    else if (bx < 40)   // K: split-3
        gemm_seg_body(lds, XH, XH, XL, WKH, WKL, WKH, out_k, KVDIM, DMODEL, 3, m0, (bx - 32) * 128, 1);
    else                // V: single-term
        gemm_seg_body(lds, XH, XH, XL, WVH, WVH, WVH, out_v, KVDIM, DMODEL, 1, m0, (bx - 40) * 128, 1);
}

// O projection (plain bf16): grid (20, 16)
__global__ __launch_bounds__(256)
void gemm_o2(const u16* __restrict__ AOH, const u16* __restrict__ WOH,
             float* __restrict__ out) {
    __shared__ u16 lds[16384];
    gemm_seg_body(lds, AOH, AOH, AOH, WOH, WOH, WOH, out, DMODEL, QDIM, 1,
                  blockIdx.y * 128, blockIdx.x * 128, 0);
}

// ---------------------------------------------------------------------------
// MFMA flash attention v8: swapped 32x32 QK^T (S^T layout, per-lane softmax).
// Block: 256 thr = 4 waves = 4 heads (one kv group) x 32 q-rows per wave.
// Grid 512: bid&7 = kvh (XCD-pinned); q-subtile qst with complement pairing
// (blocks b and b+256 co-resident on a CU have qst summing to 63 -> per-CU
// work uniform). Single-buffered K/V staging (48KB LDS -> 2 blocks/CU; the
// co-resident block's compute hides the stage drain).
// Layouts (guide-verified):
//  - 32x32x16 A/B frag: lane holds X[row=lane&31][k=(lane>>5)*8+j]
//  - 32x32 C/D: col=lane&31, row=(reg&3)+8*(reg>>2)+4*(lane>>5)
// S^T = mfma(K, Q): lane's col = its q-row -> m,l per-lane scalars; P packed
// to bf16 in-register and redistributed with 16 shfl_xor(32) per tile.
// ---------------------------------------------------------------------------
__global__ __launch_bounds__(256, 2)
void attn_mfma8(const u16* __restrict__ qh, const u16* __restrict__ ql,
                const u16* __restrict__ kh, const u16* __restrict__ kl,
                const u16* __restrict__ vt, u16* __restrict__ aoh) {
    const int bid = blockIdx.x;
    const int kvh = bid & 7;
    const int s6 = bid >> 3;                      // 0..63
    const int qst = (s6 < 32) ? s6 : 95 - s6;     // complement pairing
    const int KT = (qst >> 1) + 1;

    const int tid = threadIdx.x, lane = tid & 63, w = tid >> 6;  // w = head idx
    const int head = kvh * 4 + w;
    const int col = lane & 31;       // this lane's q-row (within 32-row subtile)
    const int hi = lane >> 5;

    __shared__ u16 SMEM[24576];      // 48KB
    u16* Khs = SMEM;                 // [64][128] swizzled (lswK)
    u16* Kls = SMEM + 8192;
    u16* Vts = SMEM + 16384;         // [128][64] swizzled (lsw CKU=8)

    // Q fragments (B-operand): lane holds Q[qst*32+col][d = db*16 + hi*8 + j]
    s16x8 qfh[8], qfl[8];
    {
        size_t qrow = (size_t)qst * 32 + col;
        const u16* qb  = qh + qrow * QDIM + (size_t)head * HD + hi * 8;
        const u16* qb2 = ql + qrow * QDIM + (size_t)head * HD + hi * 8;
        #pragma unroll
        for (int db = 0; db < 8; ++db) {
            qfh[db] = *(const s16x8*)(qb + db * 16);
            qfl[db] = *(const s16x8*)(qb2 + db * 16);
        }
    }

    f32x16 acco[4];
    #pragma unroll
    for (int dt = 0; dt < 4; ++dt) acco[dt] = (f32x16)(0.0f);
    float m = -1e30f, l = 0.f;

    const u16* kbase = kh + (size_t)kvh * S_LEN * HD;
    const u16* lbase = kl + (size_t)kvh * S_LEN * HD;
    const u16* vbase = vt + (size_t)kvh * HD * S_LEN;

    for (int kt = 0; kt < KT; ++kt) {
        // ---- stage K hi/lo [64][128] + V^T [128][64] (pre-swizzled src) ----
        for (int c = w; c < 48; c += 4) {
            int c15 = c & 15;
            int u = c15 * 64 + lane;
            if (c < 32) {
                int krow = u >> 4;
                int kb = (u & 15) ^ (krow & 15);
                size_t g = (size_t)(kt * 64 + krow) * HD + kb * 8;
                const u16* src = (c < 16 ? kbase : lbase) + g;
                u16* dst = (c < 16 ? &Khs[c15 * 512] : &Kls[c15 * 512]);
                gload16(src, dst);
            } else {
                int vrow = u >> 3;
                int vb2 = (u & 7) ^ (vrow & 7);
                gload16(vbase + (size_t)vrow * S_LEN + kt * 64 + vb2 * 8,
                        &Vts[c15 * 512]);
            }
        }
        __syncthreads();   // vmcnt(0) drained: tile ready

        // ---- S^T = K Q^T (split: kh.qh + kl.qh + kh.ql) ----
        f32x16 sf0 = (f32x16)(0.0f), sf1 = (f32x16)(0.0f);
        #pragma unroll
        for (int d = 0; d < 8; ++d) {
            int u = d * 2 + hi;
            s16x8 a0h = *(const s16x8*)&Khs[lswK(col, u)];
            s16x8 a0l = *(const s16x8*)&Kls[lswK(col, u)];
            s16x8 a1h = *(const s16x8*)&Khs[lswK(32 + col, u)];
            s16x8 a1l = *(const s16x8*)&Kls[lswK(32 + col, u)];
            sf0 = MFMA32(a0h, qfh[d], sf0);
            sf0 = MFMA32(a0l, qfh[d], sf0);
            sf0 = MFMA32(a0h, qfl[d], sf0);
            sf1 = MFMA32(a1h, qfh[d], sf1);
            sf1 = MFMA32(a1l, qfh[d], sf1);
            sf1 = MFMA32(a1h, qfl[d], sf1);
        }

        // ---- causal mask (diagonal kv-tile only) ----
        if (kt == (qst >> 1)) {
            int qg = qst * 32 + col;
            #pragma unroll
            for (int r = 0; r < 16; ++r) {
                int row = (r & 3) + 8 * (r >> 2) + 4 * hi;
                if (kt * 64 + row > qg)      sf0[r] = -1e30f;
                if (kt * 64 + 32 + row > qg) sf1[r] = -1e30f;
            }
        }

        // ---- per-lane online softmax (q = col is lane-local) ----
        float pm = sf0[0];
        #pragma unroll
        for (int r = 1; r < 16; ++r) pm = fmaxf(pm, sf0[r]);
        #pragma unroll
        for (int r = 0; r < 16; ++r) pm = fmaxf(pm, sf1[r]);
        pm = fmaxf(pm, __shfl_xor(pm, 32));   // merge lane<->lane+32 halves

        if (!__all(pm - m <= 8.0f)) {         // defer-max (T13)
            float mn = fmaxf(m, pm);
            float corr = __expf(m - mn);
            m = mn; l *= corr;
            float cv[16];
            #pragma unroll
            for (int r = 0; r < 16; ++r)
                cv[r] = __shfl(corr, (r & 3) + 8 * (r >> 2) + 4 * hi);
            #pragma unroll
            for (int dt = 0; dt < 4; ++dt)
                #pragma unroll
                for (int r = 0; r < 16; ++r) acco[dt][r] *= cv[r];
        }

        float p0[16], p1[16], sum = 0.f;
        #pragma unroll
        for (int r = 0; r < 16; ++r) { p0[r] = __expf(sf0[r] - m); sum += p0[r]; }
        #pragma unroll
        for (int r = 0; r < 16; ++r) { p1[r] = __expf(sf1[r] - m); sum += p1[r]; }
        sum += __shfl_xor(sum, 32);
        l += sum;

        // ---- pack P to bf16 + in-register redistribution to A-frag layout ----
        // holder of k: hi_h = bit2(k), r = (k&3) + 4*(k>>3); A-frag step s,
        // lane-half h needs k = ktile*32 + 16s + 8h + 0..7.
        unsigned w0[8], w1[8], x0[8], x1[8];
        #pragma unroll
        for (int i = 0; i < 8; ++i) {
            w0[i] = pk2(p0[2 * i], p0[2 * i + 1]);
            w1[i] = pk2(p1[2 * i], p1[2 * i + 1]);
        }
        #pragma unroll
        for (int i = 0; i < 8; ++i) {
            x0[i] = __shfl_xor(w0[i], 32);
            x1[i] = __shfl_xor(w1[i], 32);
        }
        union { unsigned u[4]; s16x8 v; } fa;
        s16x8 pa00, pa01, pa10, pa11;
        fa.u[0] = hi ? x0[2] : w0[0]; fa.u[1] = hi ? x0[3] : w0[1];
        fa.u[2] = hi ? w0[2] : x0[0]; fa.u[3] = hi ? w0[3] : x0[1];
        pa00 = fa.v;
        fa.u[0] = hi ? x0[6] : w0[4]; fa.u[1] = hi ? x0[7] : w0[5];
        fa.u[2] = hi ? w0[6] : x0[4]; fa.u[3] = hi ? w0[7] : x0[5];
        pa01 = fa.v;
        fa.u[0] = hi ? x1[2] : w1[0]; fa.u[1] = hi ? x1[3] : w1[1];
        fa.u[2] = hi ? w1[2] : x1[0]; fa.u[3] = hi ? w1[3] : x1[1];
        pa10 = fa.v;
        fa.u[0] = hi ? x1[6] : w1[4]; fa.u[1] = hi ? x1[7] : w1[5];
        fa.u[2] = hi ? w1[6] : x1[4]; fa.u[3] = hi ? w1[7] : x1[5];
        pa11 = fa.v;

        // ---- O += P V  (A = P frags, B = V^T from LDS) ----
        #pragma unroll
        for (int dt = 0; dt < 4; ++dt) {
            int vrow = dt * 32 + col;
            s16x8 vb00 = *(const s16x8*)&Vts[lsw(vrow, 0 + hi, 8)];
            s16x8 vb01 = *(const s16x8*)&Vts[lsw(vrow, 2 + hi, 8)];
            s16x8 vb10 = *(const s16x8*)&Vts[lsw(vrow, 4 + hi, 8)];
            s16x8 vb11 = *(const s16x8*)&Vts[lsw(vrow, 6 + hi, 8)];
            acco[dt] = MFMA32(pa00, vb00, acco[dt]);
            acco[dt] = MFMA32(pa01, vb01, acco[dt]);
            acco[dt] = MFMA32(pa10, vb10, acco[dt]);
            acco[dt] = MFMA32(pa11, vb11, acco[dt]);
        }

        __syncthreads();   // all waves done reading before restage
    }

    // ---- epilogue: normalize, LDS bounce, coalesced store ----
    float linv = 1.0f / l;
    float lv[16];
    #pragma unroll
    for (int r = 0; r < 16; ++r)
        lv[r] = __shfl(linv, (r & 3) + 8 * (r >> 2) + 4 * hi);

    u16* ob = SMEM;   // [4 heads][32 q][128 d] = 32KB (tiles dead)
    #pragma unroll
    for (int dt = 0; dt < 4; ++dt)
        #pragma unroll
        for (int r = 0; r < 16; ++r) {
            int row = (r & 3) + 8 * (r >> 2) + 4 * hi;
            ob[(w * 32 + row) * 128 + dt * 32 + col] = f2bf(acco[dt][r] * lv[r]);
        }
    __syncthreads();
    #pragma unroll
    for (int p = 0; p < 8; ++p) {
        int i = p * 256 + tid;          // 2048 int4 chunks
        int hq = i >> 4, c8 = (i & 15) * 8;
        int hh = hq >> 5, qq = hq & 31;
        size_t grow = (size_t)qst * 32 + qq;
        *(int4*)&aoh[grow * QDIM + (size_t)(kvh * 4 + hh) * HD + c8] =
            *(const int4*)&ob[hq * 128 + c8];
    }
}

// ---------------------------------------------------------------------------
extern "C" void kernel_launch(void* const* d_in, const int* in_sizes, int n_in,
                              void* d_out, int out_size, void* d_ws, size_t ws_size,
                              hipStream_t stream) {
    const float* x   = (const float*)d_in[0];
    const int*   pos = (const int*)d_in[1];
    const float* w_q = (const float*)d_in[2];
    const float* w_k = (const float*)d_in[3];
    const float* w_v = (const float*)d_in[4];
    const float* w_o = (const float*)d_in[5];

    float* out   = (float*)d_out;
    float* out_k = out + (size_t)S_LEN * DMODEL;
    float* out_v = out_k + (size_t)NKV * S_LEN * HD;

    // ---- workspace arena ----
    char* ws = (char*)d_ws;
    size_t off = 0;
    auto alloc = [&](size_t bytes) { char* p = ws + off; off += (bytes + 255) & ~255ull; return p; };
    float* cost = (float*)alloc((size_t)S_LEN * 64 * 4);
    float* sint = (float*)alloc((size_t)S_LEN * 64 * 4);
    float* Q32  = (float*)alloc((size_t)S_LEN * QDIM * 4);      // later: AOH (bf16)
    u16* XH  = (u16*)alloc((size_t)S_LEN * DMODEL * 2);         // later: KH
    u16* XL  = (u16*)alloc((size_t)S_LEN * DMODEL * 2);         // later: KL
    u16* WQH = (u16*)alloc((size_t)QDIM * DMODEL * 2);
    u16* WQL = (u16*)alloc((size_t)QDIM * DMODEL * 2);          // later: QH
    u16* WKH = (u16*)alloc((size_t)KVDIM * DMODEL * 2);
    u16* WKL = (u16*)alloc((size_t)KVDIM * DMODEL * 2);
    u16* WVH = (u16*)alloc((size_t)KVDIM * DMODEL * 2);
    u16* WOH = (u16*)alloc((size_t)DMODEL * QDIM * 2);
    u16* QL  = (u16*)alloc((size_t)S_LEN * QDIM * 2);
    u16* VT  = (u16*)alloc((size_t)NKV * HD * S_LEN * 2);
    u16* AOH = (u16*)Q32;     // alias: Q32 dead after rope_qk_split
    u16* KH  = XH;            // alias: XH dead after gemm_qkv2
    u16* KL  = XL;
    u16* QH  = WQL;           // alias: WQL dead after gemm_qkv2

    // 1. all input prep (splits + rope tables) in one launch
    prep_all<<<PREP_TOTAL / 256, 256, 0, stream>>>(
        x, w_q, w_k, w_v, w_o, pos, XH, XL, WQH, WQL, WKH, WKL, WVH, WOH, cost, sint);

    // 2. fused Q/K/V projections (segmented plain-bf16)
    gemm_qkv2<<<dim3(48, 16), 256, 0, stream>>>(
        XH, XL, WQH, WQL, WKH, WKL, WVH, Q32, out_k, out_v);

    // 3. V^T + fused rope/scale/split for q and k
    vt_transpose<<<dim3(64, 8), 256, 0, stream>>>(out_v, VT);
    rope_qk_split<<<(S_LEN * (NH + NKV) * 64) / 256, 256, 0, stream>>>(
        Q32, out_k, cost, sint, QH, QL, KH, KL);

    // 4. attention -> bf16 AO
    attn_mfma8<<<512, 256, 0, stream>>>(QH, QL, KH, KL, VT, AOH);

    // 5. O projection (plain bf16)
    gemm_o2<<<dim3(DMODEL / 128, 16), 256, 0, stream>>>(AOH, WOH, out);
}

// Round 10
// 453.419 us; speedup vs baseline: 1.0323x; 1.0323x over previous
//
#include <hip/hip_runtime.h>
#include <math.h>

#define S_LEN 2048
#define DMODEL 2560
#define NH 32
#define NKV 8
#define HD 128
#define QDIM (NH*HD)     // 4096
#define KVDIM (NKV*HD)   // 1024
#define NB (QDIM + 2*KVDIM)   // 6144 packed B rows
#define ROPE_THETA 5000000.0
#define QK_SCALE 0.08838834764831843f

typedef __attribute__((ext_vector_type(8))) short s16x8;
typedef __attribute__((ext_vector_type(4))) float f32x4;
typedef __attribute__((ext_vector_type(16))) float f32x16;
typedef unsigned short u16;

#define MFMA16(a,b,c) __builtin_amdgcn_mfma_f32_16x16x32_bf16((a),(b),(c),0,0,0)
#define MFMA32(a,b,c) __builtin_amdgcn_mfma_f32_32x32x16_bf16((a),(b),(c),0,0,0)

__device__ __forceinline__ u16 f2bf(float x) {
    union { float f; unsigned u; } v; v.f = x;
    unsigned r = v.u + 0x7FFFu + ((v.u >> 16) & 1u);
    return (u16)(r >> 16);
}
__device__ __forceinline__ float bf2f(u16 h) {
    union { unsigned u; float f; } v; v.u = ((unsigned)h) << 16;
    return v.f;
}
__device__ __forceinline__ unsigned pk2(float a, float b) {
    return (unsigned)f2bf(a) | ((unsigned)f2bf(b) << 16);
}

// Swizzled LDS index, CKU units of 8 bf16 per row; XOR low-3 bits of unit.
__device__ __forceinline__ int lsw(int row, int kb, int CKU) {
    return (((row * CKU + kb) ^ (row & 7)) << 3);
}
// K arrays: CKU=16, XOR all 4 unit bits (full 256B spread).
__device__ __forceinline__ int lswK(int row, int kb) {
    return ((row * 16 + (kb ^ (row & 15))) << 3);
}

// async global->LDS, 16B per lane; LDS dest = wave-uniform base + lane*16.
__device__ __forceinline__ void gload16(const void* g, void* l) {
    __builtin_amdgcn_global_load_lds(
        (const __attribute__((address_space(1))) void*)g,
        (__attribute__((address_space(3))) void*)l, 16, 0, 0);
}

// ---------------------------------------------------------------------------
// prep_all: all input-side elementwise work in ONE launch.
// Weights packed: WB rows [0,4096)=w_q, [4096,5120)=w_k, [5120,6144)=w_v,
// all split into hi/lo (uniform split-3 GEMM over the packed matrix).
// ---------------------------------------------------------------------------
#define N4_X   (S_LEN*DMODEL/4)      // 1310720
#define N4_WQ  (QDIM*DMODEL/4)       // 2621440
#define N4_WKV (KVDIM*DMODEL/4)      // 655360
#define N4_WO  (DMODEL*QDIM/4)       // 2621440
#define N_TAB  (S_LEN*64)            // 131072
#define PREP_TOTAL (N4_X + N4_WQ + N4_WKV + N4_WKV + N4_WO + N_TAB)

__device__ __forceinline__ void split4(const float* in, long i,
                                       u16* hi, u16* lo) {
    float4 v = ((const float4*)in)[i];
    float a[4] = {v.x, v.y, v.z, v.w};
    u16 hh[4], ll[4];
    #pragma unroll
    for (int j = 0; j < 4; ++j) {
        hh[j] = f2bf(a[j]);
        ll[j] = f2bf(a[j] - bf2f(hh[j]));
    }
    ((uint2*)hi)[i] = make_uint2((unsigned)hh[0] | ((unsigned)hh[1] << 16),
                                 (unsigned)hh[2] | ((unsigned)hh[3] << 16));
    ((uint2*)lo)[i] = make_uint2((unsigned)ll[0] | ((unsigned)ll[1] << 16),
                                 (unsigned)ll[2] | ((unsigned)ll[3] << 16));
}
__device__ __forceinline__ void cvt4(const float* in, long i, u16* out) {
    float4 v = ((const float4*)in)[i];
    u16 h0 = f2bf(v.x), h1 = f2bf(v.y), h2 = f2bf(v.z), h3 = f2bf(v.w);
    ((uint2*)out)[i] = make_uint2((unsigned)h0 | ((unsigned)h1 << 16),
                                  (unsigned)h2 | ((unsigned)h3 << 16));
}

__global__ __launch_bounds__(256)
void prep_all(const float* __restrict__ x, const float* __restrict__ w_q,
              const float* __restrict__ w_k, const float* __restrict__ w_v,
              const float* __restrict__ w_o, const int* __restrict__ pos,
              u16* __restrict__ XH, u16* __restrict__ XL,
              u16* __restrict__ WBH, u16* __restrict__ WBL,
              u16* __restrict__ WOH,
              float* __restrict__ cost, float* __restrict__ sint) {
    long i = (long)blockIdx.x * 256 + threadIdx.x;
    if (i < N4_X) { split4(x, i, XH, XL); return; }
    i -= N4_X;
    if (i < N4_WQ) { split4(w_q, i, WBH, WBL); return; }
    i -= N4_WQ;
    if (i < N4_WKV) {
        split4(w_k, i, WBH + (size_t)QDIM * DMODEL, WBL + (size_t)QDIM * DMODEL);
        return;
    }
    i -= N4_WKV;
    if (i < N4_WKV) {
        split4(w_v, i, WBH + (size_t)(QDIM + KVDIM) * DMODEL,
                       WBL + (size_t)(QDIM + KVDIM) * DMODEL);
        return;
    }
    i -= N4_WKV;
    if (i < N4_WO) { cvt4(w_o, i, WOH); return; }
    i -= N4_WO;
    if (i < N_TAB) {
        int s = (int)(i >> 6), j = (int)(i & 63);
        double inv = pow((double)ROPE_THETA, -(double)j / 64.0);
        double ang = (double)pos[s] * inv;
        cost[i] = (float)cos(ang);
        sint[i] = (float)sin(ang);
    }
}

// ---------------------------------------------------------------------------
// merged rope: q (scaled, ws) + k (in-place fp32 cache) -> bf16 hi/lo splits
// ---------------------------------------------------------------------------
__global__ __launch_bounds__(256)
void rope_qk_split(float* __restrict__ q32, float* __restrict__ k,
                   const float* __restrict__ cost, const float* __restrict__ sint,
                   u16* __restrict__ qhh, u16* __restrict__ qll,
                   u16* __restrict__ khh, u16* __restrict__ kll) {
    int idx = blockIdx.x * 256 + threadIdx.x;
    if (idx < S_LEN * NH * 64) {
        int j = idx & 63;
        int h = (idx >> 6) & 31;
        int s = idx >> 11;
        float c = cost[(s << 6) + j], sn = sint[(s << 6) + j];
        size_t base = (size_t)s * QDIM + (size_t)h * HD;
        float x1 = q32[base + j], x2 = q32[base + 64 + j];
        float y1 = (x1 * c - x2 * sn) * QK_SCALE;
        float y2 = (x2 * c + x1 * sn) * QK_SCALE;
        u16 h1 = f2bf(y1), h2 = f2bf(y2);
        qhh[base + j] = h1;      qll[base + j] = f2bf(y1 - bf2f(h1));
        qhh[base + 64 + j] = h2; qll[base + 64 + j] = f2bf(y2 - bf2f(h2));
    } else {
        idx -= S_LEN * NH * 64;
        int j = idx & 63;
        int s = (idx >> 6) & 2047;
        int h = idx >> 17;
        float c = cost[(s << 6) + j], sn = sint[(s << 6) + j];
        size_t base = ((size_t)h * S_LEN + s) * HD;
        float x1 = k[base + j], x2 = k[base + 64 + j];
        float y1 = x1 * c - x2 * sn;
        float y2 = x2 * c + x1 * sn;
        k[base + j] = y1; k[base + 64 + j] = y2;
        u16 h1 = f2bf(y1), h2 = f2bf(y2);
        khh[base + j] = h1;      kll[base + j] = f2bf(y1 - bf2f(h1));
        khh[base + 64 + j] = h2; kll[base + 64 + j] = f2bf(y2 - bf2f(h2));
    }
}

// ---------------------------------------------------------------------------
// V^T builder: v [8][2048][128] fp32 -> vt [8][128][2048] bf16 (coalesced).
// ---------------------------------------------------------------------------
__global__ __launch_bounds__(256)
void vt_transpose(const float* __restrict__ v, u16* __restrict__ vt) {
    __shared__ u16 t[64][80];
    const int kvh = blockIdx.y;
    const int st = blockIdx.x >> 1, dt = blockIdx.x & 1;
    const int tid = threadIdx.x;
    const int r = tid & 15, c4 = (tid >> 4) * 4;
    const float* vb = v + ((size_t)kvh * S_LEN + st * 64) * HD + dt * 64;
    #pragma unroll
    for (int p = 0; p < 4; ++p) {
        int row = p * 16 + r;
        float4 x = *(const float4*)&vb[(size_t)row * HD + c4];
        t[c4 + 0][row] = f2bf(x.x);
        t[c4 + 1][row] = f2bf(x.y);
        t[c4 + 2][row] = f2bf(x.z);
        t[c4 + 3][row] = f2bf(x.w);
    }
    __syncthreads();
    #pragma unroll
    for (int p = 0; p < 2; ++p) {
        int idx = p * 256 + tid;
        int dr = idx >> 3, sc = idx & 7;
        size_t o = ((size_t)kvh * HD + dt * 64 + dr) * S_LEN + st * 64 + sc * 8;
        *(int4*)&vt[o] = *(const int4*)&t[dr][sc * 8];
    }
}

// ---------------------------------------------------------------------------
// gemm_qkv3: deep-pipelined fused QKV projection.
// C[2048][6144] = sum over 3 segments of Aseg[2048][2560] . Bseg[6144][2560]^T
//   segments: A=[XH,XH,XL], B=[WBH,WBL,WBH] (split-3 fp32 emulation).
// BM=256, BN=192, BK=32; 512 thr = 8 waves (2M x 4N); per-wave C 128x48.
// 4-slot LDS ring (112KB), tile j+2 staged during window j (A phase A,
// B phase B), counted-vmcnt gate per window (T3+T4), lsw swizzle (T2),
// setprio around MFMA clusters (T5). Grid: exactly 256 blocks (1/CU);
// m-tile = bid&7 (XCD-pinned A-panel in L2).
// ---------------------------------------------------------------------------
__global__ __launch_bounds__(512, 2)
void gemm_qkv3(const u16* __restrict__ XH, const u16* __restrict__ XL,
               const u16* __restrict__ WBH, const u16* __restrict__ WBL,
               float* __restrict__ Q32, float* __restrict__ out_k,
               float* __restrict__ out_v) {
    __shared__ u16 SM[57344];        // A: 4 x 8192 u16 | B: 4 x 6144 u16
    const int bid = blockIdx.x;
    const int m0 = (bid & 7) * 256;
    const int n0 = (bid >> 3) * 192;
    const int tid = threadIdx.x, lane = tid & 63, w = tid >> 6;
    const int q4 = lane >> 4, r15 = lane & 15;
    const int wm = (w >> 2) * 128, wn = (w & 3) * 48;

    f32x4 acc[8][3];
    #pragma unroll
    for (int i = 0; i < 8; ++i)
        #pragma unroll
        for (int jj = 0; jj < 3; ++jj) acc[i][jj] = (f32x4)(0.0f);

    // stage K-tile j (32 wide) of A (256 rows, 16KB) into slot j&3.
    // LDS packing: [128 lds-rows][8 units of 8 bf16], unit pre-swizzled.
    auto stageA = [&](int j) {
        const int s = j & 3;
        const int seg = j / 80;
        const int koff = (j - seg * 80) * 32;
        const u16* Ag = (seg == 2) ? XL : XH;
        #pragma unroll
        for (int p = 0; p < 2; ++p) {
            int c = p * 8 + w;
            int u = c * 64 + lane;
            int rl = u >> 3;
            int ulog = (u & 7) ^ (rl & 7);
            int grow = m0 + rl * 2 + (ulog >> 2);
            gload16(Ag + (size_t)grow * DMODEL + koff + (ulog & 3) * 8,
                    &SM[s * 8192 + c * 512]);
        }
    };
    // stage K-tile j of B (192 rows, 12KB): waves 0-7 chunk w, waves 0-3 also 8+w.
    auto stageB = [&](int j) {
        const int s = j & 3;
        const int seg = j / 80;
        const int koff = (j - seg * 80) * 32;
        const u16* Bg = (seg == 1) ? WBL : WBH;
        {
            int u = w * 64 + lane;
            int rl = u >> 3;
            int ulog = (u & 7) ^ (rl & 7);
            int grow = n0 + rl * 2 + (ulog >> 2);
            gload16(Bg + (size_t)grow * DMODEL + koff + (ulog & 3) * 8,
                    &SM[32768 + s * 6144 + w * 512]);
        }
        if (w < 4) {
            int c = 8 + w;
            int u = c * 64 + lane;
            int rl = u >> 3;
            int ulog = (u & 7) ^ (rl & 7);
            int grow = n0 + rl * 2 + (ulog >> 2);
            gload16(Bg + (size_t)grow * DMODEL + koff + (ulog & 3) * 8,
                    &SM[32768 + s * 6144 + c * 512]);
        }
    };

    // prologue: tiles 0 and 1 in flight (per-wave loads: A 2 + B 1/2 each)
    stageA(0); stageB(0); stageA(1); stageB(1);

    const int NT = 3 * DMODEL / 32;   // 240
    for (int j = 0; j < NT; ++j) {
        const int s = j & 3;
        // gate tile j: all loads except last window's (A:2 + B:2/1) landed
        __builtin_amdgcn_sched_barrier(0);
        if (w < 4) { asm volatile("s_waitcnt vmcnt(4)" ::: "memory"); }
        else       { asm volatile("s_waitcnt vmcnt(3)" ::: "memory"); }
        __builtin_amdgcn_s_barrier();
        __builtin_amdgcn_sched_barrier(0);

        // ---- phase A: stage A(j+2) | read B-frags + A-frags 0-3 | 12 MFMA ----
        if (j + 2 < NT) stageA(j + 2);
        s16x8 bf[3];
        #pragma unroll
        for (int jj = 0; jj < 3; ++jj) {
            int row = wn + jj * 16 + r15;
            int rl = row >> 1, ulog = (row & 1) * 4 + q4;
            bf[jj] = *(const s16x8*)&SM[32768 + s * 6144 + (rl * 8 + (ulog ^ (rl & 7))) * 8];
        }
        s16x8 af[4];
        #pragma unroll
        for (int i = 0; i < 4; ++i) {
            int row = wm + i * 16 + r15;
            int rl = row >> 1, ulog = (row & 1) * 4 + q4;
            af[i] = *(const s16x8*)&SM[s * 8192 + (rl * 8 + (ulog ^ (rl & 7))) * 8];
        }
        __builtin_amdgcn_s_setprio(1);
        #pragma unroll
        for (int i = 0; i < 4; ++i)
            #pragma unroll
            for (int jj = 0; jj < 3; ++jj)
                acc[i][jj] = MFMA16(af[i], bf[jj], acc[i][jj]);
        __builtin_amdgcn_s_setprio(0);

        // ---- phase B: stage B(j+2) | read A-frags 4-7 | 12 MFMA ----
        if (j + 2 < NT) stageB(j + 2);
        s16x8 ag[4];
        #pragma unroll
        for (int i = 0; i < 4; ++i) {
            int row = wm + (i + 4) * 16 + r15;
            int rl = row >> 1, ulog = (row & 1) * 4 + q4;
            ag[i] = *(const s16x8*)&SM[s * 8192 + (rl * 8 + (ulog ^ (rl & 7))) * 8];
        }
        __builtin_amdgcn_s_setprio(1);
        #pragma unroll
        for (int i = 0; i < 4; ++i)
            #pragma unroll
            for (int jj = 0; jj < 3; ++jj)
                acc[i + 4][jj] = MFMA16(ag[i], bf[jj], acc[i + 4][jj]);
        __builtin_amdgcn_s_setprio(0);
    }

    // epilogue: D layout col = lane&15, row = (lane>>4)*4 + r; region branch
    #pragma unroll
    for (int i = 0; i < 8; ++i) {
        #pragma unroll
        for (int jj = 0; jj < 3; ++jj) {
            int col = n0 + wn + jj * 16 + r15;
            #pragma unroll
            for (int r = 0; r < 4; ++r) {
                int row = m0 + wm + i * 16 + q4 * 4 + r;
                float v = acc[i][jj][r];
                if (col < QDIM) {
                    Q32[(size_t)row * QDIM + col] = v;
                } else if (col < QDIM + KVDIM) {
                    int cc = col - QDIM;
                    out_k[((size_t)(cc >> 7) * S_LEN + row) * HD + (cc & 127)] = v;
                } else {
                    int cc = col - QDIM - KVDIM;
                    out_v[((size_t)(cc >> 7) * S_LEN + row) * HD + (cc & 127)] = v;
                }
            }
        }
    }
}

// ---------------------------------------------------------------------------
// Segmented plain-bf16 MFMA GEMM (NT). 128x128, BK=64, 32KB LDS. (O-proj)
// ---------------------------------------------------------------------------
__device__ __forceinline__ void gemm_seg_body(
    u16* lds, const u16* __restrict__ a0, const u16* __restrict__ b0,
    float* __restrict__ C, int N, int Kb, int m0, int n0) {
    u16* As = lds;
    u16* Bs = lds + 8192;
    const int tid = threadIdx.x;
    const int lane = tid & 63, w = tid >> 6;
    const int q4 = lane >> 4, r15 = lane & 15;
    const int wm = (w >> 1) * 64, wn = (w & 1) * 64;

    f32x4 acc[4][4];
    #pragma unroll
    for (int i = 0; i < 4; ++i)
        #pragma unroll
        for (int j = 0; j < 4; ++j) acc[i][j] = (f32x4)(0.0f);

    for (int k0 = 0; k0 < Kb; k0 += 64) {
        __syncthreads();
        for (int ch = w; ch < 16; ch += 4) {
            int u = ch * 64 + lane;
            int row = u >> 3;
            int kb = (u & 7) ^ (row & 7);
            size_t go = (size_t)row * Kb + k0 + kb * 8;
            gload16(a0 + (size_t)m0 * Kb + go, &As[ch * 512]);
            gload16(b0 + (size_t)n0 * Kb + go, &Bs[ch * 512]);
        }
        __syncthreads();

        #pragma unroll
        for (int kh2 = 0; kh2 < 2; ++kh2) {
            int kb = kh2 * 4 + q4;
            s16x8 ah[4], bh[4];
            #pragma unroll
            for (int i = 0; i < 4; ++i) ah[i] = *(const s16x8*)&As[lsw(wm + i * 16 + r15, kb, 8)];
            #pragma unroll
            for (int j = 0; j < 4; ++j) bh[j] = *(const s16x8*)&Bs[lsw(wn + j * 16 + r15, kb, 8)];
            #pragma unroll
            for (int i = 0; i < 4; ++i)
                #pragma unroll
                for (int j = 0; j < 4; ++j)
                    acc[i][j] = MFMA16(ah[i], bh[j], acc[i][j]);
        }
    }

    #pragma unroll
    for (int i = 0; i < 4; ++i) {
        #pragma unroll
        for (int j = 0; j < 4; ++j) {
            int col = n0 + wn + j * 16 + r15;
            #pragma unroll
            for (int r = 0; r < 4; ++r) {
                int row = m0 + wm + i * 16 + q4 * 4 + r;
                C[(size_t)row * N + col] = acc[i][j][r];
            }
        }
    }
}

// O projection (plain bf16): grid (20, 16)
__global__ __launch_bounds__(256)
void gemm_o2(const u16* __restrict__ AOH, const u16* __restrict__ WOH,
             float* __restrict__ out) {
    __shared__ u16 lds[16384];
    gemm_seg_body(lds, AOH, WOH, out, DMODEL, QDIM,
                  blockIdx.y * 128, blockIdx.x * 128);
}

// ---------------------------------------------------------------------------
// MFMA flash attention v8: swapped 32x32 QK^T (S^T layout, per-lane softmax).
// (unchanged from round 9)
// ---------------------------------------------------------------------------
__global__ __launch_bounds__(256, 2)
void attn_mfma8(const u16* __restrict__ qh, const u16* __restrict__ ql,
                const u16* __restrict__ kh, const u16* __restrict__ kl,
                const u16* __restrict__ vt, u16* __restrict__ aoh) {
    const int bid = blockIdx.x;
    const int kvh = bid & 7;
    const int s6 = bid >> 3;                      // 0..63
    const int qst = (s6 < 32) ? s6 : 95 - s6;     // complement pairing
    const int KT = (qst >> 1) + 1;

    const int tid = threadIdx.x, lane = tid & 63, w = tid >> 6;  // w = head idx
    const int head = kvh * 4 + w;
    const int col = lane & 31;
    const int hi = lane >> 5;

    __shared__ u16 SMEM[24576];      // 48KB
    u16* Khs = SMEM;                 // [64][128] swizzled (lswK)
    u16* Kls = SMEM + 8192;
    u16* Vts = SMEM + 16384;         // [128][64] swizzled (lsw CKU=8)

    s16x8 qfh[8], qfl[8];
    {
        size_t qrow = (size_t)qst * 32 + col;
        const u16* qb  = qh + qrow * QDIM + (size_t)head * HD + hi * 8;
        const u16* qb2 = ql + qrow * QDIM + (size_t)head * HD + hi * 8;
        #pragma unroll
        for (int db = 0; db < 8; ++db) {
            qfh[db] = *(const s16x8*)(qb + db * 16);
            qfl[db] = *(const s16x8*)(qb2 + db * 16);
        }
    }

    f32x16 acco[4];
    #pragma unroll
    for (int dt = 0; dt < 4; ++dt) acco[dt] = (f32x16)(0.0f);
    float m = -1e30f, l = 0.f;

    const u16* kbase = kh + (size_t)kvh * S_LEN * HD;
    const u16* lbase = kl + (size_t)kvh * S_LEN * HD;
    const u16* vbase = vt + (size_t)kvh * HD * S_LEN;

    for (int kt = 0; kt < KT; ++kt) {
        for (int c = w; c < 48; c += 4) {
            int c15 = c & 15;
            int u = c15 * 64 + lane;
            if (c < 32) {
                int krow = u >> 4;
                int kb = (u & 15) ^ (krow & 15);
                size_t g = (size_t)(kt * 64 + krow) * HD + kb * 8;
                const u16* src = (c < 16 ? kbase : lbase) + g;
                u16* dst = (c < 16 ? &Khs[c15 * 512] : &Kls[c15 * 512]);
                gload16(src, dst);
            } else {
                int vrow = u >> 3;
                int vb2 = (u & 7) ^ (vrow & 7);
                gload16(vbase + (size_t)vrow * S_LEN + kt * 64 + vb2 * 8,
                        &Vts[c15 * 512]);
            }
        }
        __syncthreads();

        f32x16 sf0 = (f32x16)(0.0f), sf1 = (f32x16)(0.0f);
        #pragma unroll
        for (int d = 0; d < 8; ++d) {
            int u = d * 2 + hi;
            s16x8 a0h = *(const s16x8*)&Khs[lswK(col, u)];
            s16x8 a0l = *(const s16x8*)&Kls[lswK(col, u)];
            s16x8 a1h = *(const s16x8*)&Khs[lswK(32 + col, u)];
            s16x8 a1l = *(const s16x8*)&Kls[lswK(32 + col, u)];
            sf0 = MFMA32(a0h, qfh[d], sf0);
            sf0 = MFMA32(a0l, qfh[d], sf0);
            sf0 = MFMA32(a0h, qfl[d], sf0);
            sf1 = MFMA32(a1h, qfh[d], sf1);
            sf1 = MFMA32(a1l, qfh[d], sf1);
            sf1 = MFMA32(a1h, qfl[d], sf1);
        }

        if (kt == (qst >> 1)) {
            int qg = qst * 32 + col;
            #pragma unroll
            for (int r = 0; r < 16; ++r) {
                int row = (r & 3) + 8 * (r >> 2) + 4 * hi;
                if (kt * 64 + row > qg)      sf0[r] = -1e30f;
                if (kt * 64 + 32 + row > qg) sf1[r] = -1e30f;
            }
        }

        float pm = sf0[0];
        #pragma unroll
        for (int r = 1; r < 16; ++r) pm = fmaxf(pm, sf0[r]);
        #pragma unroll
        for (int r = 0; r < 16; ++r) pm = fmaxf(pm, sf1[r]);
        pm = fmaxf(pm, __shfl_xor(pm, 32));

        if (!__all(pm - m <= 8.0f)) {
            float mn = fmaxf(m, pm);
            float corr = __expf(m - mn);
            m = mn; l *= corr;
            float cv[16];
            #pragma unroll
            for (int r = 0; r < 16; ++r)
                cv[r] = __shfl(corr, (r & 3) + 8 * (r >> 2) + 4 * hi);
            #pragma unroll
            for (int dt = 0; dt < 4; ++dt)
                #pragma unroll
                for (int r = 0; r < 16; ++r) acco[dt][r] *= cv[r];
        }

        float p0[16], p1[16], sum = 0.f;
        #pragma unroll
        for (int r = 0; r < 16; ++r) { p0[r] = __expf(sf0[r] - m); sum += p0[r]; }
        #pragma unroll
        for (int r = 0; r < 16; ++r) { p1[r] = __expf(sf1[r] - m); sum += p1[r]; }
        sum += __shfl_xor(sum, 32);
        l += sum;

        unsigned w0[8], w1[8], x0[8], x1[8];
        #pragma unroll
        for (int i = 0; i < 8; ++i) {
            w0[i] = pk2(p0[2 * i], p0[2 * i + 1]);
            w1[i] = pk2(p1[2 * i], p1[2 * i + 1]);
        }
        #pragma unroll
        for (int i = 0; i < 8; ++i) {
            x0[i] = __shfl_xor(w0[i], 32);
            x1[i] = __shfl_xor(w1[i], 32);
        }
        union { unsigned u[4]; s16x8 v; } fa;
        s16x8 pa00, pa01, pa10, pa11;
        fa.u[0] = hi ? x0[2] : w0[0]; fa.u[1] = hi ? x0[3] : w0[1];
        fa.u[2] = hi ? w0[2] : x0[0]; fa.u[3] = hi ? w0[3] : x0[1];
        pa00 = fa.v;
        fa.u[0] = hi ? x0[6] : w0[4]; fa.u[1] = hi ? x0[7] : w0[5];
        fa.u[2] = hi ? w0[6] : x0[4]; fa.u[3] = hi ? w0[7] : x0[5];
        pa01 = fa.v;
        fa.u[0] = hi ? x1[2] : w1[0]; fa.u[1] = hi ? x1[3] : w1[1];
        fa.u[2] = hi ? w1[2] : x1[0]; fa.u[3] = hi ? w1[3] : x1[1];
        pa10 = fa.v;
        fa.u[0] = hi ? x1[6] : w1[4]; fa.u[1] = hi ? x1[7] : w1[5];
        fa.u[2] = hi ? w1[6] : x1[4]; fa.u[3] = hi ? w1[7] : x1[5];
        pa11 = fa.v;

        #pragma unroll
        for (int dt = 0; dt < 4; ++dt) {
            int vrow = dt * 32 + col;
            s16x8 vb00 = *(const s16x8*)&Vts[lsw(vrow, 0 + hi, 8)];
            s16x8 vb01 = *(const s16x8*)&Vts[lsw(vrow, 2 + hi, 8)];
            s16x8 vb10 = *(const s16x8*)&Vts[lsw(vrow, 4 + hi, 8)];
            s16x8 vb11 = *(const s16x8*)&Vts[lsw(vrow, 6 + hi, 8)];
            acco[dt] = MFMA32(pa00, vb00, acco[dt]);
            acco[dt] = MFMA32(pa01, vb01, acco[dt]);
            acco[dt] = MFMA32(pa10, vb10, acco[dt]);
            acco[dt] = MFMA32(pa11, vb11, acco[dt]);
        }

        __syncthreads();
    }

    float linv = 1.0f / l;
    float lv[16];
    #pragma unroll
    for (int r = 0; r < 16; ++r)
        lv[r] = __shfl(linv, (r & 3) + 8 * (r >> 2) + 4 * hi);

    u16* ob = SMEM;
    #pragma unroll
    for (int dt = 0; dt < 4; ++dt)
        #pragma unroll
        for (int r = 0; r < 16; ++r) {
            int row = (r & 3) + 8 * (r >> 2) + 4 * hi;
            ob[(w * 32 + row) * 128 + dt * 32 + col] = f2bf(acco[dt][r] * lv[r]);
        }
    __syncthreads();
    #pragma unroll
    for (int p = 0; p < 8; ++p) {
        int i = p * 256 + tid;
        int hq = i >> 4, c8 = (i & 15) * 8;
        int hh = hq >> 5, qq = hq & 31;
        size_t grow = (size_t)qst * 32 + qq;
        *(int4*)&aoh[grow * QDIM + (size_t)(kvh * 4 + hh) * HD + c8] =
            *(const int4*)&ob[hq * 128 + c8];
    }
}

// ---------------------------------------------------------------------------
extern "C" void kernel_launch(void* const* d_in, const int* in_sizes, int n_in,
                              void* d_out, int out_size, void* d_ws, size_t ws_size,
                              hipStream_t stream) {
    const float* x   = (const float*)d_in[0];
    const int*   pos = (const int*)d_in[1];
    const float* w_q = (const float*)d_in[2];
    const float* w_k = (const float*)d_in[3];
    const float* w_v = (const float*)d_in[4];
    const float* w_o = (const float*)d_in[5];

    float* out   = (float*)d_out;
    float* out_k = out + (size_t)S_LEN * DMODEL;
    float* out_v = out_k + (size_t)NKV * S_LEN * HD;

    // ---- workspace arena ----
    char* ws = (char*)d_ws;
    size_t off = 0;
    auto alloc = [&](size_t bytes) { char* p = ws + off; off += (bytes + 255) & ~255ull; return p; };
    float* cost = (float*)alloc((size_t)S_LEN * 64 * 4);
    float* sint = (float*)alloc((size_t)S_LEN * 64 * 4);
    float* Q32  = (float*)alloc((size_t)S_LEN * QDIM * 4);       // later: AOH
    u16* XH  = (u16*)alloc((size_t)S_LEN * DMODEL * 2);          // later: KH
    u16* XL  = (u16*)alloc((size_t)S_LEN * DMODEL * 2);          // later: KL
    u16* WBH = (u16*)alloc((size_t)NB * DMODEL * 2);             // later: VT + QL
    u16* WBL = (u16*)alloc((size_t)NB * DMODEL * 2);             // later: QH
    u16* WOH = (u16*)alloc((size_t)DMODEL * QDIM * 2);
    u16* AOH = (u16*)Q32;
    u16* KH  = XH;
    u16* KL  = XL;
    u16* QH  = WBL;
    u16* VT  = WBH;
    u16* QL  = WBH + (size_t)NKV * HD * S_LEN;

    // 1. all input prep (splits + packed WB + rope tables) in one launch
    prep_all<<<PREP_TOTAL / 256, 256, 0, stream>>>(
        x, w_q, w_k, w_v, w_o, pos, XH, XL, WBH, WBL, WOH, cost, sint);

    // 2. fused Q/K/V projections (256x192 deep-pipelined, 256 blocks)
    gemm_qkv3<<<256, 512, 0, stream>>>(XH, XL, WBH, WBL, Q32, out_k, out_v);

    // 3. V^T + fused rope/scale/split for q and k
    vt_transpose<<<dim3(64, 8), 256, 0, stream>>>(out_v, VT);
    rope_qk_split<<<(S_LEN * (NH + NKV) * 64) / 256, 256, 0, stream>>>(
        Q32, out_k, cost, sint, QH, QL, KH, KL);

    // 4. attention -> bf16 AO
    attn_mfma8<<<512, 256, 0, stream>>>(QH, QL, KH, KL, VT, AOH);

    // 5. O projection (plain bf16)
    gemm_o2<<<dim3(DMODEL / 128, 16), 256, 0, stream>>>(AOH, WOH, out);
}

// Round 11
// 433.710 us; speedup vs baseline: 1.0792x; 1.0454x over previous
//
#include <hip/hip_runtime.h>
#include <math.h>

#define S_LEN 2048
#define DMODEL 2560
#define NH 32
#define NKV 8
#define HD 128
#define QDIM (NH*HD)     // 4096
#define KVDIM (NKV*HD)   // 1024
#define NB (QDIM + 2*KVDIM)   // 6144 packed B rows
#define ROPE_THETA 5000000.0
#define QK_SCALE 0.08838834764831843f

typedef __attribute__((ext_vector_type(8))) short s16x8;
typedef __attribute__((ext_vector_type(4))) float f32x4;
typedef __attribute__((ext_vector_type(16))) float f32x16;
typedef unsigned short u16;

#define MFMA16(a,b,c) __builtin_amdgcn_mfma_f32_16x16x32_bf16((a),(b),(c),0,0,0)
#define MFMA32(a,b,c) __builtin_amdgcn_mfma_f32_32x32x16_bf16((a),(b),(c),0,0,0)

__device__ __forceinline__ u16 f2bf(float x) {
    union { float f; unsigned u; } v; v.f = x;
    unsigned r = v.u + 0x7FFFu + ((v.u >> 16) & 1u);
    return (u16)(r >> 16);
}
__device__ __forceinline__ float bf2f(u16 h) {
    union { unsigned u; float f; } v; v.u = ((unsigned)h) << 16;
    return v.f;
}
__device__ __forceinline__ unsigned pk2(float a, float b) {
    return (unsigned)f2bf(a) | ((unsigned)f2bf(b) << 16);
}

// K arrays: [rows][16 units of 8 bf16], XOR all 4 unit bits.
__device__ __forceinline__ int lswK(int row, int kb) {
    return ((row * 16 + (kb ^ (row & 15))) << 3);
}

// async global->LDS, 16B per lane; LDS dest = wave-uniform base + lane*16.
__device__ __forceinline__ void gload16(const void* g, void* l) {
    __builtin_amdgcn_global_load_lds(
        (const __attribute__((address_space(1))) void*)g,
        (__attribute__((address_space(3))) void*)l, 16, 0, 0);
}

// ---------------------------------------------------------------------------
// prep_all: all input-side elementwise work in ONE launch.
// ---------------------------------------------------------------------------
#define N4_X   (S_LEN*DMODEL/4)
#define N4_WQ  (QDIM*DMODEL/4)
#define N4_WKV (KVDIM*DMODEL/4)
#define N4_WO  (DMODEL*QDIM/4)
#define N_TAB  (S_LEN*64)
#define PREP_TOTAL (N4_X + N4_WQ + N4_WKV + N4_WKV + N4_WO + N_TAB)

__device__ __forceinline__ void split4(const float* in, long i,
                                       u16* hi, u16* lo) {
    float4 v = ((const float4*)in)[i];
    float a[4] = {v.x, v.y, v.z, v.w};
    u16 hh[4], ll[4];
    #pragma unroll
    for (int j = 0; j < 4; ++j) {
        hh[j] = f2bf(a[j]);
        ll[j] = f2bf(a[j] - bf2f(hh[j]));
    }
    ((uint2*)hi)[i] = make_uint2((unsigned)hh[0] | ((unsigned)hh[1] << 16),
                                 (unsigned)hh[2] | ((unsigned)hh[3] << 16));
    ((uint2*)lo)[i] = make_uint2((unsigned)ll[0] | ((unsigned)ll[1] << 16),
                                 (unsigned)ll[2] | ((unsigned)ll[3] << 16));
}
__device__ __forceinline__ void cvt4(const float* in, long i, u16* out) {
    float4 v = ((const float4*)in)[i];
    u16 h0 = f2bf(v.x), h1 = f2bf(v.y), h2 = f2bf(v.z), h3 = f2bf(v.w);
    ((uint2*)out)[i] = make_uint2((unsigned)h0 | ((unsigned)h1 << 16),
                                  (unsigned)h2 | ((unsigned)h3 << 16));
}

__global__ __launch_bounds__(256)
void prep_all(const float* __restrict__ x, const float* __restrict__ w_q,
              const float* __restrict__ w_k, const float* __restrict__ w_v,
              const float* __restrict__ w_o, const int* __restrict__ pos,
              u16* __restrict__ XH, u16* __restrict__ XL,
              u16* __restrict__ WBH, u16* __restrict__ WBL,
              u16* __restrict__ WOH,
              float* __restrict__ cost, float* __restrict__ sint) {
    long i = (long)blockIdx.x * 256 + threadIdx.x;
    if (i < N4_X) { split4(x, i, XH, XL); return; }
    i -= N4_X;
    if (i < N4_WQ) { split4(w_q, i, WBH, WBL); return; }
    i -= N4_WQ;
    if (i < N4_WKV) {
        split4(w_k, i, WBH + (size_t)QDIM * DMODEL, WBL + (size_t)QDIM * DMODEL);
        return;
    }
    i -= N4_WKV;
    if (i < N4_WKV) {
        split4(w_v, i, WBH + (size_t)(QDIM + KVDIM) * DMODEL,
                       WBL + (size_t)(QDIM + KVDIM) * DMODEL);
        return;
    }
    i -= N4_WKV;
    if (i < N4_WO) { cvt4(w_o, i, WOH); return; }
    i -= N4_WO;
    if (i < N_TAB) {
        int s = (int)(i >> 6), j = (int)(i & 63);
        double inv = pow((double)ROPE_THETA, -(double)j / 64.0);
        double ang = (double)pos[s] * inv;
        cost[i] = (float)cos(ang);
        sint[i] = (float)sin(ang);
    }
}

// ---------------------------------------------------------------------------
// merged rope: q (scaled, ws) + k (in-place fp32 cache) -> bf16 hi/lo splits
// ---------------------------------------------------------------------------
__global__ __launch_bounds__(256)
void rope_qk_split(float* __restrict__ q32, float* __restrict__ k,
                   const float* __restrict__ cost, const float* __restrict__ sint,
                   u16* __restrict__ qhh, u16* __restrict__ qll,
                   u16* __restrict__ khh, u16* __restrict__ kll) {
    int idx = blockIdx.x * 256 + threadIdx.x;
    if (idx < S_LEN * NH * 64) {
        int j = idx & 63;
        int h = (idx >> 6) & 31;
        int s = idx >> 11;
        float c = cost[(s << 6) + j], sn = sint[(s << 6) + j];
        size_t base = (size_t)s * QDIM + (size_t)h * HD;
        float x1 = q32[base + j], x2 = q32[base + 64 + j];
        float y1 = (x1 * c - x2 * sn) * QK_SCALE;
        float y2 = (x2 * c + x1 * sn) * QK_SCALE;
        u16 h1 = f2bf(y1), h2 = f2bf(y2);
        qhh[base + j] = h1;      qll[base + j] = f2bf(y1 - bf2f(h1));
        qhh[base + 64 + j] = h2; qll[base + 64 + j] = f2bf(y2 - bf2f(h2));
    } else {
        idx -= S_LEN * NH * 64;
        int j = idx & 63;
        int s = (idx >> 6) & 2047;
        int h = idx >> 17;
        float c = cost[(s << 6) + j], sn = sint[(s << 6) + j];
        size_t base = ((size_t)h * S_LEN + s) * HD;
        float x1 = k[base + j], x2 = k[base + 64 + j];
        float y1 = x1 * c - x2 * sn;
        float y2 = x2 * c + x1 * sn;
        k[base + j] = y1; k[base + 64 + j] = y2;
        u16 h1 = f2bf(y1), h2 = f2bf(y2);
        khh[base + j] = h1;      kll[base + j] = f2bf(y1 - bf2f(h1));
        khh[base + 64 + j] = h2; kll[base + 64 + j] = f2bf(y2 - bf2f(h2));
    }
}

// ---------------------------------------------------------------------------
// V^T builder: v [8][2048][128] fp32 -> vt [8][128][2048] bf16 (coalesced).
// ---------------------------------------------------------------------------
__global__ __launch_bounds__(256)
void vt_transpose(const float* __restrict__ v, u16* __restrict__ vt) {
    __shared__ u16 t[64][80];
    const int kvh = blockIdx.y;
    const int st = blockIdx.x >> 1, dt = blockIdx.x & 1;
    const int tid = threadIdx.x;
    const int r = tid & 15, c4 = (tid >> 4) * 4;
    const float* vb = v + ((size_t)kvh * S_LEN + st * 64) * HD + dt * 64;
    #pragma unroll
    for (int p = 0; p < 4; ++p) {
        int row = p * 16 + r;
        float4 x = *(const float4*)&vb[(size_t)row * HD + c4];
        t[c4 + 0][row] = f2bf(x.x);
        t[c4 + 1][row] = f2bf(x.y);
        t[c4 + 2][row] = f2bf(x.z);
        t[c4 + 3][row] = f2bf(x.w);
    }
    __syncthreads();
    #pragma unroll
    for (int p = 0; p < 2; ++p) {
        int idx = p * 256 + tid;
        int dr = idx >> 3, sc = idx & 7;
        size_t o = ((size_t)kvh * HD + dt * 64 + dr) * S_LEN + st * 64 + sc * 8;
        *(int4*)&vt[o] = *(const int4*)&t[dr][sc * 8];
    }
}

// ---------------------------------------------------------------------------
// gemm_qkv3: deep-pipelined fused QKV projection (round-10, + tail-race fix).
// ---------------------------------------------------------------------------
__global__ __launch_bounds__(512, 2)
void gemm_qkv3(const u16* __restrict__ XH, const u16* __restrict__ XL,
               const u16* __restrict__ WBH, const u16* __restrict__ WBL,
               float* __restrict__ Q32, float* __restrict__ out_k,
               float* __restrict__ out_v) {
    __shared__ u16 SM[57344];        // A: 4 x 8192 u16 | B: 4 x 6144 u16
    const int bid = blockIdx.x;
    const int m0 = (bid & 7) * 256;
    const int n0 = (bid >> 3) * 192;
    const int tid = threadIdx.x, lane = tid & 63, w = tid >> 6;
    const int q4 = lane >> 4, r15 = lane & 15;
    const int wm = (w >> 2) * 128, wn = (w & 3) * 48;

    f32x4 acc[8][3];
    #pragma unroll
    for (int i = 0; i < 8; ++i)
        #pragma unroll
        for (int jj = 0; jj < 3; ++jj) acc[i][jj] = (f32x4)(0.0f);

    auto stageA = [&](int j) {
        const int s = j & 3;
        const int seg = j / 80;
        const int koff = (j - seg * 80) * 32;
        const u16* Ag = (seg == 2) ? XL : XH;
        #pragma unroll
        for (int p = 0; p < 2; ++p) {
            int c = p * 8 + w;
            int u = c * 64 + lane;
            int rl = u >> 3;
            int ulog = (u & 7) ^ (rl & 7);
            int grow = m0 + rl * 2 + (ulog >> 2);
            gload16(Ag + (size_t)grow * DMODEL + koff + (ulog & 3) * 8,
                    &SM[s * 8192 + c * 512]);
        }
    };
    auto stageB = [&](int j) {
        const int s = j & 3;
        const int seg = j / 80;
        const int koff = (j - seg * 80) * 32;
        const u16* Bg = (seg == 1) ? WBL : WBH;
        {
            int u = w * 64 + lane;
            int rl = u >> 3;
            int ulog = (u & 7) ^ (rl & 7);
            int grow = n0 + rl * 2 + (ulog >> 2);
            gload16(Bg + (size_t)grow * DMODEL + koff + (ulog & 3) * 8,
                    &SM[32768 + s * 6144 + w * 512]);
        }
        if (w < 4) {
            int c = 8 + w;
            int u = c * 64 + lane;
            int rl = u >> 3;
            int ulog = (u & 7) ^ (rl & 7);
            int grow = n0 + rl * 2 + (ulog >> 2);
            gload16(Bg + (size_t)grow * DMODEL + koff + (ulog & 3) * 8,
                    &SM[32768 + s * 6144 + c * 512]);
        }
    };

    stageA(0); stageB(0); stageA(1); stageB(1);

    const int NT = 3 * DMODEL / 32;   // 240
    for (int j = 0; j < NT; ++j) {
        const int s = j & 3;
        __builtin_amdgcn_sched_barrier(0);
        if (j + 1 < NT) {
            if (w < 4) { asm volatile("s_waitcnt vmcnt(4)" ::: "memory"); }
            else       { asm volatile("s_waitcnt vmcnt(3)" ::: "memory"); }
        } else {
            asm volatile("s_waitcnt vmcnt(0)" ::: "memory");   // tail: own loads done
        }
        __builtin_amdgcn_s_barrier();
        __builtin_amdgcn_sched_barrier(0);

        if (j + 2 < NT) stageA(j + 2);
        s16x8 bf[3];
        #pragma unroll
        for (int jj = 0; jj < 3; ++jj) {
            int row = wn + jj * 16 + r15;
            int rl = row >> 1, ulog = (row & 1) * 4 + q4;
            bf[jj] = *(const s16x8*)&SM[32768 + s * 6144 + (rl * 8 + (ulog ^ (rl & 7))) * 8];
        }
        s16x8 af[4];
        #pragma unroll
        for (int i = 0; i < 4; ++i) {
            int row = wm + i * 16 + r15;
            int rl = row >> 1, ulog = (row & 1) * 4 + q4;
            af[i] = *(const s16x8*)&SM[s * 8192 + (rl * 8 + (ulog ^ (rl & 7))) * 8];
        }
        __builtin_amdgcn_s_setprio(1);
        #pragma unroll
        for (int i = 0; i < 4; ++i)
            #pragma unroll
            for (int jj = 0; jj < 3; ++jj)
                acc[i][jj] = MFMA16(af[i], bf[jj], acc[i][jj]);
        __builtin_amdgcn_s_setprio(0);

        if (j + 2 < NT) stageB(j + 2);
        s16x8 ag[4];
        #pragma unroll
        for (int i = 0; i < 4; ++i) {
            int row = wm + (i + 4) * 16 + r15;
            int rl = row >> 1, ulog = (row & 1) * 4 + q4;
            ag[i] = *(const s16x8*)&SM[s * 8192 + (rl * 8 + (ulog ^ (rl & 7))) * 8];
        }
        __builtin_amdgcn_s_setprio(1);
        #pragma unroll
        for (int i = 0; i < 4; ++i)
            #pragma unroll
            for (int jj = 0; jj < 3; ++jj)
                acc[i + 4][jj] = MFMA16(ag[i], bf[jj], acc[i + 4][jj]);
        __builtin_amdgcn_s_setprio(0);
    }

    #pragma unroll
    for (int i = 0; i < 8; ++i) {
        #pragma unroll
        for (int jj = 0; jj < 3; ++jj) {
            int col = n0 + wn + jj * 16 + r15;
            #pragma unroll
            for (int r = 0; r < 4; ++r) {
                int row = m0 + wm + i * 16 + q4 * 4 + r;
                float v = acc[i][jj][r];
                if (col < QDIM) {
                    Q32[(size_t)row * QDIM + col] = v;
                } else if (col < QDIM + KVDIM) {
                    int cc = col - QDIM;
                    out_k[((size_t)(cc >> 7) * S_LEN + row) * HD + (cc & 127)] = v;
                } else {
                    int cc = col - QDIM - KVDIM;
                    out_v[((size_t)(cc >> 7) * S_LEN + row) * HD + (cc & 127)] = v;
                }
            }
        }
    }
}

// ---------------------------------------------------------------------------
// gemm_o3: deep-pipelined O projection (plain bf16).
// BM=128, BN=160, BK=32; 256 thr = 4 waves (2M x 2N); per-wave C 64x80.
// 4-slot LDS ring (72KB -> 2 blocks/CU), counted-vmcnt gates + tail fix.
// Grid 256: m0 = (bid&15)*128, n0 = (bid>>4)*160.
// ---------------------------------------------------------------------------
__global__ __launch_bounds__(256, 2)
void gemm_o3(const u16* __restrict__ AOH, const u16* __restrict__ WOH,
             float* __restrict__ out) {
    __shared__ u16 SM[36864];     // A: 4 x 4096 | B: 4 x 5120 (u16)
    const int bid = blockIdx.x;
    const int m0 = (bid & 15) * 128;
    const int n0 = (bid >> 4) * 160;
    const int tid = threadIdx.x, lane = tid & 63, w = tid >> 6;
    const int q4 = lane >> 4, r15 = lane & 15;
    const int wm = (w >> 1) * 64, wn = (w & 1) * 80;

    f32x4 acc[4][5];
    #pragma unroll
    for (int i = 0; i < 4; ++i)
        #pragma unroll
        for (int jj = 0; jj < 5; ++jj) acc[i][jj] = (f32x4)(0.0f);

    auto stageA = [&](int j) {
        const int s = j & 3;
        const int koff = j * 32;
        #pragma unroll
        for (int p = 0; p < 2; ++p) {
            int c = p * 4 + w;                 // 0..7
            int u = c * 64 + lane;
            int rl = u >> 3;
            int ulog = (u & 7) ^ (rl & 7);
            int grow = m0 + rl * 2 + (ulog >> 2);
            gload16(AOH + (size_t)grow * QDIM + koff + (ulog & 3) * 8,
                    &SM[s * 4096 + c * 512]);
        }
    };
    auto stageB = [&](int j) {
        const int s = j & 3;
        const int koff = j * 32;
        #pragma unroll
        for (int p = 0; p < 3; ++p) {
            int c = p * 4 + w;                 // 0..11; use <10
            if (c < 10) {
                int u = c * 64 + lane;
                int rl = u >> 3;
                int ulog = (u & 7) ^ (rl & 7);
                int grow = n0 + rl * 2 + (ulog >> 2);
                gload16(WOH + (size_t)grow * QDIM + koff + (ulog & 3) * 8,
                        &SM[16384 + s * 5120 + c * 512]);
            }
        }
    };

    stageA(0); stageB(0); stageA(1); stageB(1);

    const int NT = QDIM / 32;     // 128
    for (int j = 0; j < NT; ++j) {
        const int s = j & 3;
        __builtin_amdgcn_sched_barrier(0);
        if (j + 1 < NT) {
            if (w < 2) { asm volatile("s_waitcnt vmcnt(5)" ::: "memory"); }
            else       { asm volatile("s_waitcnt vmcnt(4)" ::: "memory"); }
        } else {
            asm volatile("s_waitcnt vmcnt(0)" ::: "memory");
        }
        __builtin_amdgcn_s_barrier();
        __builtin_amdgcn_sched_barrier(0);

        if (j + 2 < NT) stageA(j + 2);
        s16x8 bf[5];
        #pragma unroll
        for (int jj = 0; jj < 5; ++jj) {
            int row = wn + jj * 16 + r15;
            int rl = row >> 1, ulog = (row & 1) * 4 + q4;
            bf[jj] = *(const s16x8*)&SM[16384 + s * 5120 + (rl * 8 + (ulog ^ (rl & 7))) * 8];
        }
        s16x8 af01[2];
        #pragma unroll
        for (int i = 0; i < 2; ++i) {
            int row = wm + i * 16 + r15;
            int rl = row >> 1, ulog = (row & 1) * 4 + q4;
            af01[i] = *(const s16x8*)&SM[s * 4096 + (rl * 8 + (ulog ^ (rl & 7))) * 8];
        }
        __builtin_amdgcn_s_setprio(1);
        #pragma unroll
        for (int i = 0; i < 2; ++i)
            #pragma unroll
            for (int jj = 0; jj < 5; ++jj)
                acc[i][jj] = MFMA16(af01[i], bf[jj], acc[i][jj]);
        __builtin_amdgcn_s_setprio(0);

        if (j + 2 < NT) stageB(j + 2);
        s16x8 af23[2];
        #pragma unroll
        for (int i = 0; i < 2; ++i) {
            int row = wm + (i + 2) * 16 + r15;
            int rl = row >> 1, ulog = (row & 1) * 4 + q4;
            af23[i] = *(const s16x8*)&SM[s * 4096 + (rl * 8 + (ulog ^ (rl & 7))) * 8];
        }
        __builtin_amdgcn_s_setprio(1);
        #pragma unroll
        for (int i = 0; i < 2; ++i)
            #pragma unroll
            for (int jj = 0; jj < 5; ++jj)
                acc[i + 2][jj] = MFMA16(af23[i], bf[jj], acc[i + 2][jj]);
        __builtin_amdgcn_s_setprio(0);
    }

    #pragma unroll
    for (int i = 0; i < 4; ++i) {
        #pragma unroll
        for (int jj = 0; jj < 5; ++jj) {
            int col = n0 + wn + jj * 16 + r15;
            #pragma unroll
            for (int r = 0; r < 4; ++r) {
                int row = m0 + wm + i * 16 + q4 * 4 + r;
                out[(size_t)row * DMODEL + col] = acc[i][jj][r];
            }
        }
    }
}

// ---------------------------------------------------------------------------
// MFMA flash attention v9: v8's swapped 32x32 QK^T + per-lane softmax, now
// KVBLK=32 with a 3-slot LDS ring (72KB -> 2 blocks/CU) and counted-vmcnt
// gates (T3+T4): per window [vmcnt(6)][barrier][stage kt+2][compute kt].
// Block: 256 thr = 4 waves = 4 heads x 32 q-rows (subtile qst).
// Grid 512: bid&7 = kvh; complement pairing (qst, 63-qst) -> 65 windows/CU.
// V slot layout: [64 R][8 units], unit(d,kb) at slot ((d&1)*4+kb)^(R&7),
// R = d>>1 (conflict-optimal, trivially invertible for staging).
// ---------------------------------------------------------------------------
__global__ __launch_bounds__(256, 2)
void attn_mfma9(const u16* __restrict__ qh, const u16* __restrict__ ql,
                const u16* __restrict__ kh, const u16* __restrict__ kl,
                const u16* __restrict__ vt, u16* __restrict__ aoh) {
    const int bid = blockIdx.x;
    const int kvh = bid & 7;
    const int s6 = bid >> 3;                      // 0..63
    const int qst = (s6 < 32) ? s6 : 95 - s6;     // 0..63
    const int KT = qst + 1;                       // 32-wide kv tiles

    const int tid = threadIdx.x, lane = tid & 63, w = tid >> 6;  // w = head
    const int head = kvh * 4 + w;
    const int col = lane & 31;       // this lane's q-row within subtile
    const int hi = lane >> 5;

    __shared__ u16 SMEM[36864];      // 72KB: 3 slots x (Khs 4096|Kls 4096|Vts 4096)

    // Q fragments (B-operand): lane holds Q[qst*32+col][d = db*16 + hi*8 + j]
    s16x8 qfh[8], qfl[8];
    {
        size_t qrow = (size_t)qst * 32 + col;
        const u16* qb  = qh + qrow * QDIM + (size_t)head * HD + hi * 8;
        const u16* qb2 = ql + qrow * QDIM + (size_t)head * HD + hi * 8;
        #pragma unroll
        for (int db = 0; db < 8; ++db) {
            qfh[db] = *(const s16x8*)(qb + db * 16);
            qfl[db] = *(const s16x8*)(qb2 + db * 16);
        }
    }

    f32x16 acco[4];
    #pragma unroll
    for (int dt = 0; dt < 4; ++dt) acco[dt] = (f32x16)(0.0f);
    float m = -1e30f, l = 0.f;

    const u16* kbase = kh + (size_t)kvh * S_LEN * HD;
    const u16* lbase = kl + (size_t)kvh * S_LEN * HD;
    const u16* vbase = vt + (size_t)kvh * HD * S_LEN;

    // 24 chunks of 1KB per tile: 0..7 Khs, 8..15 Kls, 16..23 Vts; 6/wave.
    auto stage = [&](int kt, int slot) {
        u16* S = SMEM + slot * 12288;
        #pragma unroll
        for (int i = 0; i < 6; ++i) {
            int c = w + 4 * i;
            if (c < 16) {
                int cc = c & 7;
                int u = cc * 64 + lane;
                int krow = u >> 4;                       // 0..31
                int kb = (u & 15) ^ (krow & 15);
                size_t g = (size_t)(kt * 32 + krow) * HD + kb * 8;
                if (c < 8) gload16(kbase + g, S + cc * 512);
                else       gload16(lbase + g, S + 4096 + cc * 512);
            } else {
                int cc = c - 16;
                int u = cc * 64 + lane;
                int R = u >> 3, s3 = u & 7;
                int g3 = s3 ^ (R & 7);
                int d = R * 2 + (g3 >> 2);               // 0..127
                int kb = g3 & 3;
                gload16(vbase + (size_t)d * S_LEN + kt * 32 + kb * 8,
                        S + 8192 + cc * 512);
            }
        }
    };

    stage(0, 0);
    if (KT > 1) stage(1, 1);

    for (int kt = 0; kt < KT; ++kt) {
        const int slot = kt % 3;
        // gate: own 6 loads of tile kt retired (allow kt+1's 6 in flight);
        // tail window must drain fully.
        __builtin_amdgcn_sched_barrier(0);
        if (kt + 1 < KT) { asm volatile("s_waitcnt vmcnt(6)" ::: "memory"); }
        else             { asm volatile("s_waitcnt vmcnt(0)" ::: "memory"); }
        __builtin_amdgcn_s_barrier();    // all waves' tile-kt loads done;
                                         // all waves past compute kt-1
        __builtin_amdgcn_sched_barrier(0);
        if (kt + 2 < KT) stage(kt + 2, (kt + 2) % 3);   // slot (kt-1)%3: safe

        u16* Khs = SMEM + slot * 12288;
        u16* Kls = Khs + 4096;
        u16* Vts = Khs + 8192;

        // ---- S^T = K Q^T (split-3), two independent 12-MFMA chains ----
        f32x16 sfA = (f32x16)(0.0f), sfB = (f32x16)(0.0f);
        __builtin_amdgcn_s_setprio(1);
        #pragma unroll
        for (int d = 0; d < 4; ++d) {
            int u = d * 2 + hi;
            s16x8 a0h = *(const s16x8*)&Khs[lswK(col, u)];
            s16x8 a0l = *(const s16x8*)&Kls[lswK(col, u)];
            sfA = MFMA32(a0h, qfh[d], sfA);
            sfA = MFMA32(a0l, qfh[d], sfA);
            sfA = MFMA32(a0h, qfl[d], sfA);
        }
        #pragma unroll
        for (int d = 4; d < 8; ++d) {
            int u = d * 2 + hi;
            s16x8 a0h = *(const s16x8*)&Khs[lswK(col, u)];
            s16x8 a0l = *(const s16x8*)&Kls[lswK(col, u)];
            sfB = MFMA32(a0h, qfh[d], sfB);
            sfB = MFMA32(a0l, qfh[d], sfB);
            sfB = MFMA32(a0h, qfl[d], sfB);
        }
        __builtin_amdgcn_s_setprio(0);
        f32x16 sf0 = sfA + sfB;

        // ---- causal mask (diagonal tile only) ----
        if (kt == qst) {
            #pragma unroll
            for (int r = 0; r < 16; ++r) {
                int row = (r & 3) + 8 * (r >> 2) + 4 * hi;
                if (row > col) sf0[r] = -1e30f;
            }
        }

        // ---- per-lane online softmax (q = col is lane-local) ----
        float pm = sf0[0];
        #pragma unroll
        for (int r = 1; r < 16; ++r) pm = fmaxf(pm, sf0[r]);
        pm = fmaxf(pm, __shfl_xor(pm, 32));

        if (!__all(pm - m <= 8.0f)) {         // defer-max (T13)
            float mn = fmaxf(m, pm);
            float corr = __expf(m - mn);
            m = mn; l *= corr;
            float cv[16];
            #pragma unroll
            for (int r = 0; r < 16; ++r)
                cv[r] = __shfl(corr, (r & 3) + 8 * (r >> 2) + 4 * hi);
            #pragma unroll
            for (int dt = 0; dt < 4; ++dt)
                #pragma unroll
                for (int r = 0; r < 16; ++r) acco[dt][r] *= cv[r];
        }

        float p0[16], sum = 0.f;
        #pragma unroll
        for (int r = 0; r < 16; ++r) { p0[r] = __expf(sf0[r] - m); sum += p0[r]; }
        sum += __shfl_xor(sum, 32);
        l += sum;

        // ---- pack P to bf16 + in-register redistribution (v8-verified) ----
        unsigned w0[8], x0[8];
        #pragma unroll
        for (int i = 0; i < 8; ++i) w0[i] = pk2(p0[2 * i], p0[2 * i + 1]);
        #pragma unroll
        for (int i = 0; i < 8; ++i) x0[i] = __shfl_xor(w0[i], 32);
        union { unsigned u[4]; s16x8 v; } fa;
        s16x8 pa00, pa01;
        fa.u[0] = hi ? x0[2] : w0[0]; fa.u[1] = hi ? x0[3] : w0[1];
        fa.u[2] = hi ? w0[2] : x0[0]; fa.u[3] = hi ? w0[3] : x0[1];
        pa00 = fa.v;
        fa.u[0] = hi ? x0[6] : w0[4]; fa.u[1] = hi ? x0[7] : w0[5];
        fa.u[2] = hi ? w0[6] : x0[4]; fa.u[3] = hi ? w0[7] : x0[5];
        pa01 = fa.v;

        // ---- O += P V ----
        __builtin_amdgcn_s_setprio(1);
        #pragma unroll
        for (int dt = 0; dt < 4; ++dt) {
            int d = dt * 32 + col;
            int R = d >> 1, r7 = R & 7, par = (d & 1) * 4;
            s16x8 vb00 = *(const s16x8*)&Vts[((R << 3) + ((par | hi) ^ r7)) << 3];
            s16x8 vb01 = *(const s16x8*)&Vts[((R << 3) + ((par | (2 + hi)) ^ r7)) << 3];
            acco[dt] = MFMA32(pa00, vb00, acco[dt]);
            acco[dt] = MFMA32(pa01, vb01, acco[dt]);
        }
        __builtin_amdgcn_s_setprio(0);
        // no end barrier: next window's top barrier orders slot reuse
    }

    // ---- epilogue: normalize, LDS bounce, coalesced store ----
    __syncthreads();     // all waves done with ring before SMEM reuse
    float linv = 1.0f / l;
    float lv[16];
    #pragma unroll
    for (int r = 0; r < 16; ++r)
        lv[r] = __shfl(linv, (r & 3) + 8 * (r >> 2) + 4 * hi);

    u16* ob = SMEM;      // [4 heads][32 q][128 d] = 32KB
    #pragma unroll
    for (int dt = 0; dt < 4; ++dt)
        #pragma unroll
        for (int r = 0; r < 16; ++r) {
            int row = (r & 3) + 8 * (r >> 2) + 4 * hi;
            ob[(w * 32 + row) * 128 + dt * 32 + col] = f2bf(acco[dt][r] * lv[r]);
        }
    __syncthreads();
    #pragma unroll
    for (int p = 0; p < 8; ++p) {
        int i = p * 256 + tid;
        int hq = i >> 4, c8 = (i & 15) * 8;
        int hh = hq >> 5, qq = hq & 31;
        size_t grow = (size_t)qst * 32 + qq;
        *(int4*)&aoh[grow * QDIM + (size_t)(kvh * 4 + hh) * HD + c8] =
            *(const int4*)&ob[hq * 128 + c8];
    }
}

// ---------------------------------------------------------------------------
extern "C" void kernel_launch(void* const* d_in, const int* in_sizes, int n_in,
                              void* d_out, int out_size, void* d_ws, size_t ws_size,
                              hipStream_t stream) {
    const float* x   = (const float*)d_in[0];
    const int*   pos = (const int*)d_in[1];
    const float* w_q = (const float*)d_in[2];
    const float* w_k = (const float*)d_in[3];
    const float* w_v = (const float*)d_in[4];
    const float* w_o = (const float*)d_in[5];

    float* out   = (float*)d_out;
    float* out_k = out + (size_t)S_LEN * DMODEL;
    float* out_v = out_k + (size_t)NKV * S_LEN * HD;

    // ---- workspace arena ----
    char* ws = (char*)d_ws;
    size_t off = 0;
    auto alloc = [&](size_t bytes) { char* p = ws + off; off += (bytes + 255) & ~255ull; return p; };
    float* cost = (float*)alloc((size_t)S_LEN * 64 * 4);
    float* sint = (float*)alloc((size_t)S_LEN * 64 * 4);
    float* Q32  = (float*)alloc((size_t)S_LEN * QDIM * 4);       // later: AOH
    u16* XH  = (u16*)alloc((size_t)S_LEN * DMODEL * 2);          // later: KH
    u16* XL  = (u16*)alloc((size_t)S_LEN * DMODEL * 2);          // later: KL
    u16* WBH = (u16*)alloc((size_t)NB * DMODEL * 2);             // later: VT + QL
    u16* WBL = (u16*)alloc((size_t)NB * DMODEL * 2);             // later: QH
    u16* WOH = (u16*)alloc((size_t)DMODEL * QDIM * 2);
    u16* AOH = (u16*)Q32;
    u16* KH  = XH;
    u16* KL  = XL;
    u16* QH  = WBL;
    u16* VT  = WBH;
    u16* QL  = WBH + (size_t)NKV * HD * S_LEN;

    // 1. all input prep (splits + packed WB + rope tables) in one launch
    prep_all<<<PREP_TOTAL / 256, 256, 0, stream>>>(
        x, w_q, w_k, w_v, w_o, pos, XH, XL, WBH, WBL, WOH, cost, sint);

    // 2. fused Q/K/V projections (256x192 deep-pipelined, 256 blocks)
    gemm_qkv3<<<256, 512, 0, stream>>>(XH, XL, WBH, WBL, Q32, out_k, out_v);

    // 3. V^T + fused rope/scale/split for q and k
    vt_transpose<<<dim3(64, 8), 256, 0, stream>>>(out_v, VT);
    rope_qk_split<<<(S_LEN * (NH + NKV) * 64) / 256, 256, 0, stream>>>(
        Q32, out_k, cost, sint, QH, QL, KH, KL);

    // 4. attention -> bf16 AO (3-slot ring, counted-vmcnt pipeline)
    attn_mfma9<<<512, 256, 0, stream>>>(QH, QL, KH, KL, VT, AOH);

    // 5. O projection (deep-pipelined)
    gemm_o3<<<256, 256, 0, stream>>>(AOH, WOH, out);
}